// Round 1
// baseline (138.479 us; speedup 1.0000x reference)
//
#include <hip/hip_runtime.h>
#include <hip/hip_bf16.h>
#include <float.h>

#define N 8192
#define D 128
#define NCHUNK 8
#define CHUNK (N / NCHUNK)      // 1024 cols per chunk
#define WPB 4                   // waves per block
#define WCOLS (CHUNK / WPB)     // 256 cols per wave
#define NPART (NCHUNK * WPB)    // 32 partial slots per row

typedef unsigned short u16;
typedef __attribute__((ext_vector_type(8))) short bf16x8;
typedef __attribute__((ext_vector_type(4))) float f32x4;

__device__ inline u16 f32_to_bf16_rtne(float f) {
  union { float f; unsigned int u; } c; c.f = f;
  unsigned int u = c.u;
  u += 0x7FFFu + ((u >> 16) & 1u);   // round to nearest even
  return (u16)(u >> 16);
}

// ---------------- kernel 1: f32 -> bf16 convert ----------------
__global__ __launch_bounds__(256) void convert_kernel(const float* __restrict__ P,
                                                      u16* __restrict__ Pb) {
  int i = blockIdx.x * 256 + threadIdx.x;      // one float4 per thread
  float4 v = reinterpret_cast<const float4*>(P)[i];
  uint2 o;
  o.x = (unsigned)f32_to_bf16_rtne(v.x) | ((unsigned)f32_to_bf16_rtne(v.y) << 16);
  o.y = (unsigned)f32_to_bf16_rtne(v.z) | ((unsigned)f32_to_bf16_rtne(v.w) << 16);
  reinterpret_cast<uint2*>(Pb)[i] = o;
}

// ---------------- kernel 2: fused sim-tile + masked min/max ----------------
// grid: (N/16 row-tiles, NCHUNK col-chunks), 256 threads (4 waves).
// Each wave: the block's 16 rows x its own 256-col slice.
__global__ __launch_bounds__(256) void margin_main(const u16* __restrict__ Pb,
                                                   const int* __restrict__ y,
                                                   float* __restrict__ pmin,
                                                   float* __restrict__ pmax) {
  const int wave = threadIdx.x >> 6;
  const int lane = threadIdx.x & 63;
  const int c15 = lane & 15;       // col-within-tile (B/C) and row-within-tile (A)
  const int g   = lane >> 4;       // k-group for A/B frags; row-group for C

  const int row0  = blockIdx.x * 16;
  const int colw0 = blockIdx.y * CHUNK + wave * WCOLS;

  // A fragments: lane holds row (row0+c15), k = ks*32 + g*8 .. +8
  bf16x8 afrag[4];
  const u16* arow = Pb + (size_t)(row0 + c15) * D + g * 8;
#pragma unroll
  for (int ks = 0; ks < 4; ++ks)
    afrag[ks] = *reinterpret_cast<const bf16x8*>(arow + ks * 32);

  // C rows owned by this lane: row0 + g*4 + r
  int rowIdx[4], yrow[4];
#pragma unroll
  for (int r = 0; r < 4; ++r) {
    rowIdx[r] = row0 + g * 4 + r;
    yrow[r]   = y[rowIdx[r]];
  }

  float mins[4], maxd[4];
#pragma unroll
  for (int r = 0; r < 4; ++r) { mins[r] = FLT_MAX; maxd[r] = -FLT_MAX; }

#pragma unroll 2
  for (int ct = 0; ct < WCOLS; ct += 16) {
    const int col = colw0 + ct + c15;
    const u16* brow = Pb + (size_t)col * D + g * 8;
    bf16x8 bfrag[4];
#pragma unroll
    for (int ks = 0; ks < 4; ++ks)
      bfrag[ks] = *reinterpret_cast<const bf16x8*>(brow + ks * 32);

    f32x4 acc = {0.f, 0.f, 0.f, 0.f};
#pragma unroll
    for (int ks = 0; ks < 4; ++ks)
      acc = __builtin_amdgcn_mfma_f32_16x16x32_bf16(afrag[ks], bfrag[ks], acc, 0, 0, 0);

    const int ycol = y[col];
#pragma unroll
    for (int r = 0; r < 4; ++r) {
      const float v = acc[r];
      if (ycol == yrow[r]) {
        if (col != rowIdx[r]) mins[r] = fminf(mins[r], v);   // same class, not self
      } else {
        maxd[r] = fmaxf(maxd[r], v);                          // different class
      }
    }
  }

  // butterfly min/max across the 16 lanes sharing g (they cover different cols)
#pragma unroll
  for (int off = 1; off < 16; off <<= 1) {
#pragma unroll
    for (int r = 0; r < 4; ++r) {
      mins[r] = fminf(mins[r], __shfl_xor(mins[r], off, 64));
      maxd[r] = fmaxf(maxd[r], __shfl_xor(maxd[r], off, 64));
    }
  }

  if (c15 == 0) {
    const int slot = blockIdx.y * WPB + wave;
#pragma unroll
    for (int r = 0; r < 4; ++r) {
      pmin[(size_t)rowIdx[r] * NPART + slot] = mins[r];
      pmax[(size_t)rowIdx[r] * NPART + slot] = maxd[r];
    }
  }
}

// ---------------- kernel 3: per-row hinge + block partial sums ----------------
__global__ __launch_bounds__(256) void loss_kernel(const float* __restrict__ pmin,
                                                   const float* __restrict__ pmax,
                                                   float* __restrict__ blockSums) {
  const int row = blockIdx.x * 256 + threadIdx.x;
  float mn = FLT_MAX, mx = -FLT_MAX;
#pragma unroll
  for (int s = 0; s < NPART; ++s) {
    mn = fminf(mn, pmin[(size_t)row * NPART + s]);
    mx = fmaxf(mx, pmax[(size_t)row * NPART + s]);
  }
  if (mn == FLT_MAX)  mn = 0.f;   // row has no same-class partner
  if (mx == -FLT_MAX) mx = 0.f;   // row has no diff-class partner
  float loss = fmaxf(0.f, mn + mx + 1.0f);   // TAU = 1.0

#pragma unroll
  for (int off = 32; off >= 1; off >>= 1)
    loss += __shfl_down(loss, off, 64);
  __shared__ float wsum[4];
  if ((threadIdx.x & 63) == 0) wsum[threadIdx.x >> 6] = loss;
  __syncthreads();
  if (threadIdx.x == 0)
    blockSums[blockIdx.x] = wsum[0] + wsum[1] + wsum[2] + wsum[3];
}

// ---------------- kernel 4: final mean ----------------
__global__ __launch_bounds__(64) void finalize_kernel(const float* __restrict__ blockSums,
                                                      float* __restrict__ out) {
  float v = (threadIdx.x < N / 256) ? blockSums[threadIdx.x] : 0.f;
#pragma unroll
  for (int off = 32; off >= 1; off >>= 1)
    v += __shfl_down(v, off, 64);
  if (threadIdx.x == 0) out[0] = v / (float)N;
}

extern "C" void kernel_launch(void* const* d_in, const int* in_sizes, int n_in,
                              void* d_out, int out_size, void* d_ws, size_t ws_size,
                              hipStream_t stream) {
  const float* P = (const float*)d_in[0];
  const int*   y = (const int*)d_in[1];
  float* out = (float*)d_out;

  // ws layout: Pb (2 MB) | pmin (1 MB) | pmax (1 MB) | blockSums (128 B)
  u16*   Pb        = (u16*)d_ws;
  float* pmin      = (float*)((char*)d_ws + (size_t)N * D * sizeof(u16));
  float* pmax      = pmin + (size_t)N * NPART;
  float* blockSums = pmax + (size_t)N * NPART;

  convert_kernel<<<dim3(N * D / 4 / 256), 256, 0, stream>>>(P, Pb);
  margin_main<<<dim3(N / 16, NCHUNK), 256, 0, stream>>>(Pb, y, pmin, pmax);
  loss_kernel<<<dim3(N / 256), 256, 0, stream>>>(pmin, pmax, blockSums);
  finalize_kernel<<<1, 64, 0, stream>>>(blockSums, out);
}

// Round 2
// 47.321 us; speedup vs baseline: 2.9264x; 2.9264x over previous
//
#include <hip/hip_runtime.h>
#include <hip/hip_bf16.h>
#include <float.h>

#define N 8192
#define D 128
#define BM 128                       // rows per block (4 waves x 32)
#define BN 64                        // cols per LDS tile
#define GY 16                        // col-chunks (grid.y)
#define COLS_PER_BLOCK (N / GY)      // 512
#define TILES (COLS_PER_BLOCK / BN)  // 8
#define NPART GY                     // partial slots per row
#define LOSS_BLOCKS (N / 256)        // 32

typedef unsigned short u16;
typedef unsigned int u32;
typedef __attribute__((ext_vector_type(8))) short bf16x8;
typedef __attribute__((ext_vector_type(4))) float f32x4;

typedef const __attribute__((address_space(1))) u32 glb_u32;
typedef __attribute__((address_space(3))) u32 lds_u32;

__device__ inline u16 f32_to_bf16_rtne(float f) {
  union { float f; unsigned int u; } c; c.f = f;
  unsigned int u = c.u;
  u += 0x7FFFu + ((u >> 16) & 1u);
  return (u16)(u >> 16);
}

// ---------------- kernel 1: f32 -> bf16 convert ----------------
__global__ __launch_bounds__(256) void convert_kernel(const float* __restrict__ P,
                                                      u16* __restrict__ Pb) {
  int i = blockIdx.x * 256 + threadIdx.x;
  float4 v = reinterpret_cast<const float4*>(P)[i];
  uint2 o;
  o.x = (unsigned)f32_to_bf16_rtne(v.x) | ((unsigned)f32_to_bf16_rtne(v.y) << 16);
  o.y = (unsigned)f32_to_bf16_rtne(v.z) | ((unsigned)f32_to_bf16_rtne(v.w) << 16);
  reinterpret_cast<uint2*>(Pb)[i] = o;
}

// ---------------- kernel 2: LDS-staged fused sim + masked min/max ----------------
// grid (N/BM, GY), 256 threads (4 waves). Wave w owns rows R0+w*32..+32 (2 rowgroups
// of 16). Per tile: 64 cols x 256B staged contiguous->LDS (swizzled), shared by all
// 4 waves. Swizzle: LDS_off(c,o) = c*256 + (o ^ ((c&15)<<4))  (16B-chunk involution).
__global__ __launch_bounds__(256) void margin_main(const u16* __restrict__ Pb,
                                                   const int* __restrict__ y,
                                                   float* __restrict__ pmin,
                                                   float* __restrict__ pmax) {
  __shared__ __align__(16) char ldsB[2][BN * 256];   // 2 x 16KB
  __shared__ int ldsY[2][BN];

  const int tid  = threadIdx.x;
  const int w    = tid >> 6;
  const int lane = tid & 63;
  const int c15  = lane & 15;
  const int g    = lane >> 4;

  const int R0 = blockIdx.x * BM;
  const int C0 = blockIdx.y * COLS_PER_BLOCK;
  const char* pbb = (const char*)Pb;

  // A fragments (held in regs for all tiles): lane holds row R0+w*32+rg*16+c15,
  // bytes kk*64 + g*16 .. +16  (same layout validated in round 1)
  bf16x8 afrag[2][4];
#pragma unroll
  for (int rg = 0; rg < 2; ++rg) {
    const char* ap = pbb + (size_t)(R0 + w * 32 + rg * 16 + c15) * 256 + g * 16;
#pragma unroll
    for (int kk = 0; kk < 4; ++kk)
      afrag[rg][kk] = *reinterpret_cast<const bf16x8*>(ap + kk * 64);
  }

  int rowI[2][4], yrow[2][4];
#pragma unroll
  for (int rg = 0; rg < 2; ++rg)
#pragma unroll
    for (int r = 0; r < 4; ++r) {
      rowI[rg][r] = R0 + w * 32 + rg * 16 + g * 4 + r;
      yrow[rg][r] = y[rowI[rg][r]];
    }

  float mins[2][4], maxd[2][4];
#pragma unroll
  for (int rg = 0; rg < 2; ++rg)
#pragma unroll
    for (int r = 0; r < 4; ++r) { mins[rg][r] = FLT_MAX; maxd[rg][r] = -FLT_MAX; }

  // stage tile t into buffer buf: 16KB B (4 glds x 1KB per wave) + 64 ints y (wave 0)
  auto STAGE = [&](int buf, int t) {
    const char* gb = pbb + (size_t)(C0 + t * BN) * 256;
#pragma unroll
    for (int j = 0; j < 4; ++j) {
      const int L = ((w * 4 + j) * 64 + lane) * 16;  // linear LDS byte this lane fills
      const int c = L >> 8;
      const int o = L & 255;
      const int src = c * 256 + (o ^ ((c & 15) << 4));  // inverse-swizzled source
      char* ldst = &ldsB[buf][(w * 4 + j) * 1024];      // wave-uniform base
      __builtin_amdgcn_global_load_lds((glb_u32*)(gb + src), (lds_u32*)ldst, 16, 0, 0);
    }
    if (w == 0)
      __builtin_amdgcn_global_load_lds((glb_u32*)(y + C0 + t * BN + lane),
                                       (lds_u32*)&ldsY[buf][0], 4, 0, 0);
  };

  STAGE(0, 0);

  for (int t = 0; t < TILES; ++t) {
    const int buf = t & 1;
    asm volatile("s_waitcnt vmcnt(0)" ::: "memory");
    __syncthreads();                       // staged buf ready for everyone
    if (t + 1 < TILES) STAGE(buf ^ 1, t + 1);

    const char* Bb = &ldsB[buf][0];
    const int ct0 = C0 + t * BN;
#pragma unroll
    for (int s = 0; s < 4; ++s) {          // 16-col subtiles
      const int c = s * 16 + c15;          // col within tile for B frag (c&15 == c15)
      bf16x8 bf[4];
#pragma unroll
      for (int kk = 0; kk < 4; ++kk) {
        const int off = c * 256 + (((g * 16) | (kk * 64)) ^ (c15 << 4));
        bf[kk] = *reinterpret_cast<const bf16x8*>(Bb + off);
      }
      f32x4 acc0 = {0.f, 0.f, 0.f, 0.f}, acc1 = {0.f, 0.f, 0.f, 0.f};
#pragma unroll
      for (int kk = 0; kk < 4; ++kk) {
        acc0 = __builtin_amdgcn_mfma_f32_16x16x32_bf16(afrag[0][kk], bf[kk], acc0, 0, 0, 0);
        acc1 = __builtin_amdgcn_mfma_f32_16x16x32_bf16(afrag[1][kk], bf[kk], acc1, 0, 0, 0);
      }
      const int col  = ct0 + c;
      const int ycol = ldsY[buf][c];
#pragma unroll
      for (int r = 0; r < 4; ++r) {
        {
          const float v = acc0[r];
          if (ycol == yrow[0][r]) {
            if (col != rowI[0][r]) mins[0][r] = fminf(mins[0][r], v);
          } else maxd[0][r] = fmaxf(maxd[0][r], v);
        }
        {
          const float v = acc1[r];
          if (ycol == yrow[1][r]) {
            if (col != rowI[1][r]) mins[1][r] = fminf(mins[1][r], v);
          } else maxd[1][r] = fmaxf(maxd[1][r], v);
        }
      }
    }
    __syncthreads();                       // everyone done reading buf
  }

  // butterfly over the 16 col-lanes (bits 0-3; stays within g-group)
#pragma unroll
  for (int off = 1; off < 16; off <<= 1)
#pragma unroll
    for (int rg = 0; rg < 2; ++rg)
#pragma unroll
      for (int r = 0; r < 4; ++r) {
        mins[rg][r] = fminf(mins[rg][r], __shfl_xor(mins[rg][r], off, 64));
        maxd[rg][r] = fmaxf(maxd[rg][r], __shfl_xor(maxd[rg][r], off, 64));
      }

  if (c15 == 0) {
#pragma unroll
    for (int rg = 0; rg < 2; ++rg)
#pragma unroll
      for (int r = 0; r < 4; ++r) {
        pmin[(size_t)blockIdx.y * N + rowI[rg][r]] = mins[rg][r];  // slot-major
        pmax[(size_t)blockIdx.y * N + rowI[rg][r]] = maxd[rg][r];
      }
  }
}

// ---------------- kernel 3: combine partials, hinge, block sums ----------------
__global__ __launch_bounds__(256) void loss_kernel(const float* __restrict__ pmin,
                                                   const float* __restrict__ pmax,
                                                   float* __restrict__ blockSums) {
  const int row = blockIdx.x * 256 + threadIdx.x;
  float mn = FLT_MAX, mx = -FLT_MAX;
#pragma unroll
  for (int s = 0; s < NPART; ++s) {            // slot-major: coalesced
    mn = fminf(mn, pmin[(size_t)s * N + row]);
    mx = fmaxf(mx, pmax[(size_t)s * N + row]);
  }
  if (mn == FLT_MAX)  mn = 0.f;
  if (mx == -FLT_MAX) mx = 0.f;
  float loss = fmaxf(0.f, mn + mx + 1.0f);     // TAU = 1.0

#pragma unroll
  for (int off = 32; off >= 1; off >>= 1)
    loss += __shfl_down(loss, off, 64);
  __shared__ float wsum[4];
  if ((threadIdx.x & 63) == 0) wsum[threadIdx.x >> 6] = loss;
  __syncthreads();
  if (threadIdx.x == 0)
    blockSums[blockIdx.x] = wsum[0] + wsum[1] + wsum[2] + wsum[3];
}

// ---------------- kernel 4: final mean ----------------
__global__ __launch_bounds__(64) void finalize_kernel(const float* __restrict__ blockSums,
                                                      float* __restrict__ out) {
  float v = (threadIdx.x < LOSS_BLOCKS) ? blockSums[threadIdx.x] : 0.f;
#pragma unroll
  for (int off = 32; off >= 1; off >>= 1)
    v += __shfl_down(v, off, 64);
  if (threadIdx.x == 0) out[0] = v / (float)N;
}

extern "C" void kernel_launch(void* const* d_in, const int* in_sizes, int n_in,
                              void* d_out, int out_size, void* d_ws, size_t ws_size,
                              hipStream_t stream) {
  const float* P = (const float*)d_in[0];
  const int*   y = (const int*)d_in[1];
  float* out = (float*)d_out;

  // ws: Pb (2MB) | pmin (512KB) | pmax (512KB) | blockSums
  u16*   Pb        = (u16*)d_ws;
  float* pmin      = (float*)((char*)d_ws + (size_t)N * D * sizeof(u16));
  float* pmax      = pmin + (size_t)N * NPART;
  float* blockSums = pmax + (size_t)N * NPART;

  convert_kernel<<<dim3(N * D / 4 / 256), 256, 0, stream>>>(P, Pb);
  margin_main<<<dim3(N / BM, GY), 256, 0, stream>>>(Pb, y, pmin, pmax);
  loss_kernel<<<dim3(LOSS_BLOCKS), 256, 0, stream>>>(pmin, pmax, blockSums);
  finalize_kernel<<<1, 64, 0, stream>>>(blockSums, out);
}

// Round 3
// 38.560 us; speedup vs baseline: 3.5912x; 1.2272x over previous
//
#include <hip/hip_runtime.h>
#include <hip/hip_bf16.h>
#include <float.h>

#define N 8192
#define D 128
#define BM 256                       // rows per block: 4 waves x 64 rows
#define BN 64                        // cols per LDS tile
#define GY 16                        // col-chunks (grid.y)
#define COLS_PER_BLOCK (N / GY)      // 512
#define TILES (COLS_PER_BLOCK / BN)  // 8
#define NPART GY
#define LOSS_BLOCKS (N / 256)        // 32

typedef unsigned short u16;
typedef unsigned int u32;
typedef __attribute__((ext_vector_type(8))) short bf16x8;
typedef __attribute__((ext_vector_type(4))) float f32x4;

typedef const __attribute__((address_space(1))) u32 glb_u32;
typedef __attribute__((address_space(3))) u32 lds_u32;

__device__ inline u16 f32_to_bf16_rtne(float f) {
  union { float f; unsigned int u; } c; c.f = f;
  unsigned int u = c.u;
  u += 0x7FFFu + ((u >> 16) & 1u);
  return (u16)(u >> 16);
}

// ---------------- kernel 1: f32 -> bf16 convert ----------------
__global__ __launch_bounds__(256) void convert_kernel(const float* __restrict__ P,
                                                      u16* __restrict__ Pb) {
  int i = blockIdx.x * 256 + threadIdx.x;
  float4 v = reinterpret_cast<const float4*>(P)[i];
  uint2 o;
  o.x = (unsigned)f32_to_bf16_rtne(v.x) | ((unsigned)f32_to_bf16_rtne(v.y) << 16);
  o.y = (unsigned)f32_to_bf16_rtne(v.z) | ((unsigned)f32_to_bf16_rtne(v.w) << 16);
  reinterpret_cast<uint2*>(Pb)[i] = o;
}

// ---------------- kernel 2 body: 3-deep pipelined fused sim + min/max ----------
// Swizzle (validated r2): LDS_off(c,o) = c*256 + (o ^ ((c&15)<<4)), 16B involution,
// applied on the global SOURCE at stage time and on the ds_read address (rule 21).
template <bool DIAG>
__device__ __forceinline__ void pipeline(const char* __restrict__ pbb,
                                         const int* __restrict__ y,
                                         float* __restrict__ pmin,
                                         float* __restrict__ pmax,
                                         char* ldsB, int* ldsY,
                                         int R0, int C0, int slot) {
  const int tid  = threadIdx.x;
  const int w    = tid >> 6;
  const int lane = tid & 63;
  const int c15  = lane & 15;
  const int g    = lane >> 4;

  // ---- prologue: y for the block's 512 cols (wave w: ints [w*128, +128), 2 glds)
  {
    const int* gy = y + C0 + w * 128 + lane;
    lds_u32* dst = (lds_u32*)(ldsY + w * 128);
    __builtin_amdgcn_global_load_lds((glb_u32*)gy,        dst,      4, 0, 0);
    __builtin_amdgcn_global_load_lds((glb_u32*)(gy + 64), dst + 64, 4, 0, 0);
  }

  // stage tile t into buffer buf: 16KB, 4 glds x 1KB per wave, uniform count
  auto STAGE = [&](int buf, int t) {
    const char* gb = pbb + (size_t)(C0 + t * BN) * 256;
    char* base = ldsB + buf * (BN * 256);
#pragma unroll
    for (int j = 0; j < 4; ++j) {
      const int L = ((w * 4 + j) * 64 + lane) * 16;    // linear LDS byte
      const int c = L >> 8;
      const int o = L & 255;
      const int src = c * 256 + (o ^ ((c & 15) << 4)); // inverse-swizzled source
      __builtin_amdgcn_global_load_lds((glb_u32*)(gb + src),
                                       (lds_u32*)(base + (w * 4 + j) * 1024), 16, 0, 0);
    }
  };

  STAGE(0, 0);
  STAGE(1, 1);

  // ---- A fragments: 4 rowgroups x 16 rows, K=128 (64 VGPRs, resident)
  bf16x8 afrag[4][4];
#pragma unroll
  for (int rg = 0; rg < 4; ++rg) {
    const char* ap = pbb + (size_t)(R0 + w * 64 + rg * 16 + c15) * 256 + g * 16;
#pragma unroll
    for (int kk = 0; kk < 4; ++kk)
      afrag[rg][kk] = *reinterpret_cast<const bf16x8*>(ap + kk * 64);
  }

  int rowI[4][4], yrow[4][4];
#pragma unroll
  for (int rg = 0; rg < 4; ++rg)
#pragma unroll
    for (int r = 0; r < 4; ++r) {
      rowI[rg][r] = R0 + w * 64 + rg * 16 + g * 4 + r;
      yrow[rg][r] = y[rowI[rg][r]];
    }

  float mins[4][4], maxd[4][4];
#pragma unroll
  for (int rg = 0; rg < 4; ++rg)
#pragma unroll
    for (int r = 0; r < 4; ++r) { mins[rg][r] = FLT_MAX; maxd[rg][r] = -FLT_MAX; }

#pragma unroll 1
  for (int t = 0; t < TILES; ++t) {
    // counted vmcnt: my stage(t) landed; stage(t+1)'s 4 loads stay in flight
    if (t + 1 < TILES) asm volatile("s_waitcnt vmcnt(4)" ::: "memory");
    else               asm volatile("s_waitcnt vmcnt(0)" ::: "memory");
    __builtin_amdgcn_s_barrier();          // all waves' stage(t) landed;
                                           // buf[(t+2)%3] free (read in t-1)
    if (t + 2 < TILES) STAGE((t + 2) % 3, t + 2);

    const char* Bb = ldsB + (t % 3) * (BN * 256);
    const int ct0 = t * BN;                // col offset within block
#pragma unroll
    for (int s = 0; s < 4; ++s) {
      const int c = s * 16 + c15;
      bf16x8 bf[4];
#pragma unroll
      for (int kk = 0; kk < 4; ++kk) {
        const int off = c * 256 + (((g * 16) | (kk * 64)) ^ (c15 << 4));
        bf[kk] = *reinterpret_cast<const bf16x8*>(Bb + off);
      }
      f32x4 acc[4];
#pragma unroll
      for (int rg = 0; rg < 4; ++rg) acc[rg] = (f32x4){0.f, 0.f, 0.f, 0.f};
#pragma unroll
      for (int kk = 0; kk < 4; ++kk)
#pragma unroll
        for (int rg = 0; rg < 4; ++rg)
          acc[rg] = __builtin_amdgcn_mfma_f32_16x16x32_bf16(afrag[rg][kk], bf[kk],
                                                            acc[rg], 0, 0, 0);
      const int colB = ct0 + c;
      const int col  = C0 + colB;
      const int ycol = ldsY[colB];
#pragma unroll
      for (int rg = 0; rg < 4; ++rg)
#pragma unroll
        for (int r = 0; r < 4; ++r) {
          const float v = acc[rg][r];
          const bool same = (ycol == yrow[rg][r]);
          bool okmin = same;
          if (DIAG) okmin = same && (col != rowI[rg][r]);
          const float cmin = okmin ? v : FLT_MAX;
          const float cmax = same ? -FLT_MAX : v;
          mins[rg][r] = fminf(mins[rg][r], cmin);
          maxd[rg][r] = fmaxf(maxd[rg][r], cmax);
        }
    }
  }

  // butterfly over the 16 col-lanes (bits 0-3)
#pragma unroll
  for (int off = 1; off < 16; off <<= 1)
#pragma unroll
    for (int rg = 0; rg < 4; ++rg)
#pragma unroll
      for (int r = 0; r < 4; ++r) {
        mins[rg][r] = fminf(mins[rg][r], __shfl_xor(mins[rg][r], off, 64));
        maxd[rg][r] = fmaxf(maxd[rg][r], __shfl_xor(maxd[rg][r], off, 64));
      }

  if (c15 == 0) {
#pragma unroll
    for (int rg = 0; rg < 4; ++rg)
#pragma unroll
      for (int r = 0; r < 4; ++r) {
        pmin[(size_t)slot * N + rowI[rg][r]] = mins[rg][r];
        pmax[(size_t)slot * N + rowI[rg][r]] = maxd[rg][r];
      }
  }
}

__global__ __launch_bounds__(256, 2) void margin_main(const u16* __restrict__ Pb,
                                                      const int* __restrict__ y,
                                                      float* __restrict__ pmin,
                                                      float* __restrict__ pmax) {
  __shared__ __align__(16) char ldsB[3][BN * 256];   // 48 KB, 3-deep
  __shared__ int ldsY[COLS_PER_BLOCK];               // 2 KB
  const int R0 = blockIdx.x * BM;
  const int C0 = blockIdx.y * COLS_PER_BLOCK;
  if ((unsigned)(R0 - C0) < (unsigned)COLS_PER_BLOCK)
    pipeline<true>((const char*)Pb, y, pmin, pmax, &ldsB[0][0], ldsY, R0, C0, blockIdx.y);
  else
    pipeline<false>((const char*)Pb, y, pmin, pmax, &ldsB[0][0], ldsY, R0, C0, blockIdx.y);
}

// ---------------- kernel 3: combine partials, hinge, block sums ----------------
__global__ __launch_bounds__(256) void loss_kernel(const float* __restrict__ pmin,
                                                   const float* __restrict__ pmax,
                                                   float* __restrict__ blockSums) {
  const int row = blockIdx.x * 256 + threadIdx.x;
  float mn = FLT_MAX, mx = -FLT_MAX;
#pragma unroll
  for (int s = 0; s < NPART; ++s) {            // slot-major: coalesced
    mn = fminf(mn, pmin[(size_t)s * N + row]);
    mx = fmaxf(mx, pmax[(size_t)s * N + row]);
  }
  if (mn == FLT_MAX)  mn = 0.f;
  if (mx == -FLT_MAX) mx = 0.f;
  float loss = fmaxf(0.f, mn + mx + 1.0f);     // TAU = 1.0

#pragma unroll
  for (int off = 32; off >= 1; off >>= 1)
    loss += __shfl_down(loss, off, 64);
  __shared__ float wsum[4];
  if ((threadIdx.x & 63) == 0) wsum[threadIdx.x >> 6] = loss;
  __syncthreads();
  if (threadIdx.x == 0)
    blockSums[blockIdx.x] = wsum[0] + wsum[1] + wsum[2] + wsum[3];
}

// ---------------- kernel 4: final mean ----------------
__global__ __launch_bounds__(64) void finalize_kernel(const float* __restrict__ blockSums,
                                                      float* __restrict__ out) {
  float v = (threadIdx.x < LOSS_BLOCKS) ? blockSums[threadIdx.x] : 0.f;
#pragma unroll
  for (int off = 32; off >= 1; off >>= 1)
    v += __shfl_down(v, off, 64);
  if (threadIdx.x == 0) out[0] = v / (float)N;
}

extern "C" void kernel_launch(void* const* d_in, const int* in_sizes, int n_in,
                              void* d_out, int out_size, void* d_ws, size_t ws_size,
                              hipStream_t stream) {
  const float* P = (const float*)d_in[0];
  const int*   y = (const int*)d_in[1];
  float* out = (float*)d_out;

  u16*   Pb        = (u16*)d_ws;
  float* pmin      = (float*)((char*)d_ws + (size_t)N * D * sizeof(u16));
  float* pmax      = pmin + (size_t)N * NPART;
  float* blockSums = pmax + (size_t)N * NPART;

  convert_kernel<<<dim3(N * D / 4 / 256), 256, 0, stream>>>(P, Pb);
  margin_main<<<dim3(N / BM, GY), 256, 0, stream>>>(Pb, y, pmin, pmax);
  loss_kernel<<<dim3(LOSS_BLOCKS), 256, 0, stream>>>(pmin, pmax, blockSums);
  finalize_kernel<<<1, 64, 0, stream>>>(blockSums, out);
}